// Round 6
// baseline (30225.345 us; speedup 1.0000x reference)
//
#include <hip/hip_runtime.h>
#include <hip/hip_fp16.h>
#include <cstddef>

// FDRNN: fuzzy -> FC(200->1024->1024->1024->128) -> 2-layer tanh RNN (H=512)
// B=64, S=512 -> 32768 rows.
//
// R5 post-mortem: compiler sank the "register-resident" W loads back into the
// loop (VGPR=128 < the 144 needed; FETCH flat -> L2 re-reads, not spill).
// Step = max(L2 ~5850, LDS h-broadcast 8 waves x 64 b128 ~6144) ~= 6300 cyc.
// R6: 256 threads x 2 outputs (4 waves -> h-broadcast halves to 3072 cyc),
// VGPR cap 512 (launch_bounds(256,1)), W pinned via asm "+v" (un-remat-able):
// 40 j-groups x 2 rows resident (320 VGPR), 24 groups streamed (~3700 cyc).

typedef _Float16 half8 __attribute__((ext_vector_type(8)));
typedef float f32x4 __attribute__((ext_vector_type(4)));

__device__ __forceinline__ void gld_lds16(const void* g, void* lds) {
  __builtin_amdgcn_global_load_lds(
      (const __attribute__((address_space(1))) unsigned int*)g,
      (__attribute__((address_space(3))) unsigned int*)lds, 16, 0, 0);
}

// ---------------- fuzzy (fp16 out, K padded 200->256) ----------------
__global__ void fuzzy16(const float* __restrict__ x, const float* __restrict__ fp,
                        _Float16* __restrict__ z, int nrows) {
  int idx = blockIdx.x * blockDim.x + threadIdx.x;
  if (idx >= nrows * 256) return;
  int r = idx >> 8;
  int f = idx & 255;
  float v = 0.f;
  if (f < 200) {
    int i = f % 50;
    float xv = x[r * 50 + i];
    float mu = fp[2 * f];
    float sg = fp[2 * f + 1];
    float d = xv - mu;
    v = expf(-(d * d) / sg);
  }
  z[idx] = (_Float16)v;
}

// ---------------- weight fp32 -> fp16 (with optional K zero-pad) -------------
__global__ void cvt_w16(const float* __restrict__ W, _Float16* __restrict__ O,
                        int rows, int kin, int kpad) {
  int idx = blockIdx.x * blockDim.x + threadIdx.x;
  if (idx >= rows * kpad) return;
  int r = idx / kpad;
  int k = idx - r * kpad;
  O[idx] = (k < kin) ? (_Float16)W[(size_t)r * kin + k] : (_Float16)0.f;
}

// ---------------- MFMA fp16 GEMM: C16[M][N] = A16[M][K] @ W16[N][K]^T + b ----
__global__ __launch_bounds__(256) void gemm16(
    const _Float16* __restrict__ A, const _Float16* __restrict__ W,
    const float* __restrict__ b1, const float* __restrict__ b2,
    _Float16* __restrict__ C, int M, int N, int K) {
  __shared__ _Float16 As[128 * 32];
  __shared__ _Float16 Bs[128 * 32];
  const int tid = threadIdx.x;
  const int bm = blockIdx.y * 128;
  const int bn = blockIdx.x * 128;
  const int lane = tid & 63;
  const int wv = tid >> 6;
  const int wm = (wv >> 1) * 64;
  const int wn = (wv & 1) * 64;
  const int frow = lane & 15;
  const int fk = (lane >> 4) * 8;

  const int srow = tid >> 2;
  const int scol = (tid & 3) * 16;  // bytes
  const char* gA = (const char*)(A + (size_t)(bm + srow) * K) + scol;
  const char* gB = (const char*)(W + (size_t)(bn + srow) * K) + scol;
  const size_t rowstep = (size_t)64 * K * 2;
  char* lA = (char*)As + tid * 16;
  char* lB = (char*)Bs + tid * 16;

  f32x4 acc[4][4] = {};

  for (int k0 = 0; k0 < K; k0 += 32) {
    gld_lds16(gA, lA);
    gld_lds16(gA + rowstep, lA + 4096);
    gld_lds16(gB, lB);
    gld_lds16(gB + rowstep, lB + 4096);
    gA += 64;
    gB += 64;
    __syncthreads();
    half8 af[4], bf[4];
#pragma unroll
    for (int i = 0; i < 4; i++) {
      af[i] = *(const half8*)(As + (wm + i * 16 + frow) * 32 + fk);
      bf[i] = *(const half8*)(Bs + (wn + i * 16 + frow) * 32 + fk);
    }
#pragma unroll
    for (int i = 0; i < 4; i++)
#pragma unroll
      for (int j = 0; j < 4; j++)
        acc[i][j] = __builtin_amdgcn_mfma_f32_16x16x32_f16(af[i], bf[j], acc[i][j], 0, 0, 0);
    __syncthreads();
  }

  float bias[4];
#pragma unroll
  for (int j = 0; j < 4; j++) {
    int col = bn + wn + j * 16 + frow;
    bias[j] = b1[col] + (b2 ? b2[col] : 0.f);
  }
  const int r0 = (lane >> 4) * 4;
#pragma unroll
  for (int i = 0; i < 4; i++) {
#pragma unroll
    for (int r = 0; r < 4; r++) {
      int row = bm + wm + i * 16 + r0 + r;
      _Float16* Cp = C + (size_t)row * N + bn + wn + frow;
#pragma unroll
      for (int j = 0; j < 4; j++)
        Cp[j * 16] = (_Float16)(acc[i][j][r] + bias[j]);
    }
  }
}

// ---------------- RNN weight pack: pair layout for 2-output threads ----------
// QP[g*512 + t*2 + r] = 8 fp16 = w_hh[t + 256*r][8g .. 8g+8), g in [0,64)
__global__ void pack_whh_pairs(const float* __restrict__ W, float4* __restrict__ QP) {
  int idx = blockIdx.x * blockDim.x + threadIdx.x;
  if (idx >= 32768) return;
  int g = idx >> 9;
  int rem = idx & 511;
  int t = rem >> 1;
  int r = rem & 1;
  const float* src = W + (size_t)(t + 256 * r) * 512 + g * 8;
  __align__(16) __half2 p[4];
#pragma unroll
  for (int k = 0; k < 4; k++)
    p[k] = __halves2half2(__float2half(src[2 * k]), __float2half(src[2 * k + 1]));
  QP[idx] = *(const float4*)p;
}

typedef _Float16 v2h __attribute__((ext_vector_type(2)));

__device__ __forceinline__ float dot2acc(float wbits, float hbits, float acc) {
#if __has_builtin(__builtin_amdgcn_fdot2)
  return __builtin_amdgcn_fdot2(__builtin_bit_cast(v2h, wbits),
                                __builtin_bit_cast(v2h, hbits), acc, false);
#else
  float2 wf = __half22float2(__builtin_bit_cast(__half2, wbits));
  float2 hf = __half22float2(__builtin_bit_cast(__half2, hbits));
  return fmaf(wf.x, hf.x, fmaf(wf.y, hf.y, acc));
#endif
}

// ---------------- RNN: 64 blocks x 256 threads, 2 outputs/thread -------------
// j-groups (8 fp16): [0,GR) pinned in VGPRs, [GR,64) streamed from L2.
#define GR 40
#define PIN(v) asm volatile("" : "+v"(v.x), "+v"(v.y), "+v"(v.z), "+v"(v.w))
#define PIN2(a) PIN(wa[a]); PIN(wb[a])

__global__ __launch_bounds__(256, 1) void rnn_reg_k(
    const _Float16* __restrict__ pre,  // [512][512] per batch, biases folded
    const float4* __restrict__ QP,     // packed pair-layout fp16 w_hh
    float* __restrict__ out32,         // nullable: final fp32 output
    _Float16* __restrict__ out16) {    // nullable: fp16 h for next-layer GEMM
  const int b = blockIdx.x;
  const int tid = threadIdx.x;
  __shared__ __half hsh[512];

  const float4* qp = QP + tid * 2;
  float4 wa[GR], wb[GR];
#pragma unroll
  for (int g = 0; g < GR; g++) {
    wa[g] = qp[g * 512];
    wb[g] = qp[g * 512 + 1];
  }
  // Pin: values become asm-defined -> cannot be rematerialized/sunk into loop.
  PIN2(0); PIN2(1); PIN2(2); PIN2(3); PIN2(4); PIN2(5); PIN2(6); PIN2(7);
  PIN2(8); PIN2(9); PIN2(10); PIN2(11); PIN2(12); PIN2(13); PIN2(14); PIN2(15);
  PIN2(16); PIN2(17); PIN2(18); PIN2(19); PIN2(20); PIN2(21); PIN2(22); PIN2(23);
  PIN2(24); PIN2(25); PIN2(26); PIN2(27); PIN2(28); PIN2(29); PIN2(30); PIN2(31);
  PIN2(32); PIN2(33); PIN2(34); PIN2(35); PIN2(36); PIN2(37); PIN2(38); PIN2(39);

  hsh[tid] = __float2half(0.f);
  hsh[tid + 256] = __float2half(0.f);
  __syncthreads();

  const _Float16* preb = pre + (size_t)b * 262144;
  float* ob32 = out32 ? out32 + (size_t)b * 262144 : nullptr;
  _Float16* ob16 = out16 ? out16 + (size_t)b * 262144 : nullptr;
  const float4* hs4 = (const float4*)hsh;

  for (int t = 0; t < 512; t++) {
    float a0 = (float)preb[t * 512 + tid];
    float c0 = (float)preb[t * 512 + tid + 256];
    float a1 = 0.f, a2 = 0.f, a3 = 0.f;
    float c1 = 0.f, c2 = 0.f, c3 = 0.f;
    // resident section: j 0..8*GR
#pragma unroll
    for (int g = 0; g < GR; g++) {
      float4 hq = hs4[g];
      a0 = dot2acc(wa[g].x, hq.x, a0);
      a1 = dot2acc(wa[g].y, hq.y, a1);
      a2 = dot2acc(wa[g].z, hq.z, a2);
      a3 = dot2acc(wa[g].w, hq.w, a3);
      c0 = dot2acc(wb[g].x, hq.x, c0);
      c1 = dot2acc(wb[g].y, hq.y, c1);
      c2 = dot2acc(wb[g].z, hq.z, c2);
      c3 = dot2acc(wb[g].w, hq.w, c3);
    }
    // streamed section: chunks of 4 groups to bound live ranges
#pragma unroll
    for (int cc = 0; cc < 6; cc++) {
      float4 qa[4], qb[4];
#pragma unroll
      for (int k = 0; k < 4; k++) {
        int g = GR + cc * 4 + k;
        qa[k] = qp[g * 512];
        qb[k] = qp[g * 512 + 1];
      }
#pragma unroll
      for (int k = 0; k < 4; k++) {
        int g = GR + cc * 4 + k;
        float4 hq = hs4[g];
        a0 = dot2acc(qa[k].x, hq.x, a0);
        a1 = dot2acc(qa[k].y, hq.y, a1);
        a2 = dot2acc(qa[k].z, hq.z, a2);
        a3 = dot2acc(qa[k].w, hq.w, a3);
        c0 = dot2acc(qb[k].x, hq.x, c0);
        c1 = dot2acc(qb[k].y, hq.y, c1);
        c2 = dot2acc(qb[k].z, hq.z, c2);
        c3 = dot2acc(qb[k].w, hq.w, c3);
      }
    }
    float hn0 = tanhf((a0 + a1) + (a2 + a3));
    float hn1 = tanhf((c0 + c1) + (c2 + c3));
    __syncthreads();                    // all h reads of step t done
    hsh[tid] = __float2half(hn0);
    hsh[tid + 256] = __float2half(hn1);
    if (ob32) {
      ob32[t * 512 + tid] = hn0;
      ob32[t * 512 + tid + 256] = hn1;
    }
    if (ob16) {
      ob16[t * 512 + tid] = (_Float16)hn0;
      ob16[t * 512 + tid + 256] = (_Float16)hn1;
    }
    __syncthreads();                    // h_t visible
  }
}

extern "C" void kernel_launch(void* const* d_in, const int* in_sizes, int n_in,
                              void* d_out, int out_size, void* d_ws, size_t ws_size,
                              hipStream_t stream) {
  const float* x     = (const float*)d_in[0];
  const float* fp    = (const float*)d_in[1];
  const float* fc0_w = (const float*)d_in[2];
  const float* fc0_b = (const float*)d_in[3];
  const float* fc1_w = (const float*)d_in[4];
  const float* fc1_b = (const float*)d_in[5];
  const float* fc2_w = (const float*)d_in[6];
  const float* fc2_b = (const float*)d_in[7];
  const float* fc3_w = (const float*)d_in[8];
  const float* fc3_b = (const float*)d_in[9];
  const float* w_ih0 = (const float*)d_in[10];
  const float* w_hh0 = (const float*)d_in[11];
  const float* b_ih0 = (const float*)d_in[12];
  const float* b_hh0 = (const float*)d_in[13];
  const float* w_ih1 = (const float*)d_in[14];
  const float* w_hh1 = (const float*)d_in[15];
  const float* b_ih1 = (const float*)d_in[16];
  const float* b_hh1 = (const float*)d_in[17];
  float* out = (float*)d_out;
  float* ws  = (float*)d_ws;

  // ws layout (float offsets). Total ~73.8 MB.
  _Float16* preH = (_Float16*)ws;                    // [32768][512] fp16
  float* U = ws + 8388608;
  _Float16* h16 = (_Float16*)U;                      // RNN phase: [32768][512]
  _Float16* t0  = (_Float16*)U;                      // FC phase: [8192][1024]
  float* R2 = U + 4194304;
  _Float16* t1  = (_Float16*)R2;                     // [8192][1024]
  _Float16* zc  = (_Float16*)R2;                     // [8192][256]
  _Float16* f3  = (_Float16*)(R2 + 1048576);         // [8192][128]
  float* wbase = ws + 16777216;
  float4*   QP0   = (float4*)wbase;
  float4*   QP1   = (float4*)(wbase + 131072);
  _Float16* fc0h  = (_Float16*)(wbase + 262144);
  _Float16* fc1h  = (_Float16*)(wbase + 393216);
  _Float16* fc2h  = (_Float16*)(wbase + 917504);
  _Float16* fc3h  = (_Float16*)(wbase + 1441792);
  _Float16* wih0h = (_Float16*)(wbase + 1507328);
  _Float16* wih1h = (_Float16*)(wbase + 1540096);

  pack_whh_pairs<<<128, 256, 0, stream>>>(w_hh0, QP0);
  pack_whh_pairs<<<128, 256, 0, stream>>>(w_hh1, QP1);
  cvt_w16<<<1024, 256, 0, stream>>>(fc0_w, fc0h, 1024, 200, 256);
  cvt_w16<<<4096, 256, 0, stream>>>(fc1_w, fc1h, 1024, 1024, 1024);
  cvt_w16<<<4096, 256, 0, stream>>>(fc2_w, fc2h, 1024, 1024, 1024);
  cvt_w16<<<512, 256, 0, stream>>>(fc3_w, fc3h, 128, 1024, 1024);
  cvt_w16<<<256, 256, 0, stream>>>(w_ih0, wih0h, 512, 128, 128);
  cvt_w16<<<1024, 256, 0, stream>>>(w_ih1, wih1h, 512, 512, 512);

  const int CH = 8192;  // 32768 rows in 4 chunks
  for (int c = 0; c < 4; c++) {
    size_t row0 = (size_t)c * CH;
    fuzzy16<<<CH, 256, 0, stream>>>(x + row0 * 50, fp, zc, CH);
    gemm16<<<dim3(8, 64), 256, 0, stream>>>(zc, fc0h, fc0_b, nullptr, t0, CH, 1024, 256);
    gemm16<<<dim3(8, 64), 256, 0, stream>>>(t0, fc1h, fc1_b, nullptr, t1, CH, 1024, 1024);
    gemm16<<<dim3(8, 64), 256, 0, stream>>>(t1, fc2h, fc2_b, nullptr, t0, CH, 1024, 1024);
    gemm16<<<dim3(1, 64), 256, 0, stream>>>(t0, fc3h, fc3_b, nullptr, f3, CH, 128, 1024);
    gemm16<<<dim3(4, 64), 256, 0, stream>>>(f3, wih0h, b_ih0, b_hh0,
                                            preH + row0 * 512, CH, 512, 128);
  }

  // RNN layer 0: preH -> h16 (fp16, feeds layer-1 input projection)
  rnn_reg_k<<<64, 256, 0, stream>>>(preH, QP0, nullptr, h16);
  // pre1 = h0 @ w_ih1^T + b_ih1 + b_hh1 (fp16 out into preH)
  gemm16<<<dim3(4, 256), 256, 0, stream>>>(h16, wih1h, b_ih1, b_hh1, preH, 32768, 512, 512);
  // RNN layer 1: preH -> final fp32 output
  rnn_reg_k<<<64, 256, 0, stream>>>(preH, QP1, out, nullptr);
}